// Round 6
// baseline (339.939 us; speedup 1.0000x reference)
//
#include <hip/hip_runtime.h>
#include <hip/hip_bf16.h>

// B=4, S=2048, D_MODEL=1024, H=16, HEAD=64. Inputs fp32, output fp32.
#define S_LEN 2048
#define DM    1024
#define NH    16
#define HD    64

typedef __attribute__((ext_vector_type(8))) short short8;   // 8 bf16 (MFMA A/B frag)
typedef __attribute__((ext_vector_type(4))) short short4v;  // 4 bf16 (8B store)
typedef __attribute__((ext_vector_type(4))) float f32x4;    // MFMA C/D frag

// fp32 -> bf16 RNE (weight/output paths)
__device__ __forceinline__ short f2bf(float f) {
    union { float f; unsigned u; } x; x.f = f;
    unsigned u = x.u;
    return (short)((u + 0x7FFFu + ((u >> 16) & 1u)) >> 16);
}
// round-half-up variants (2 VALU; bias negligible for continuous data)
__device__ __forceinline__ short f2bf_ru(float f) {
    return (short)((__float_as_uint(f) + 0x8000u) >> 16);
}
__device__ __forceinline__ unsigned pk2bf(float a, float b) {
    unsigned ua = __float_as_uint(a) + 0x8000u;
    unsigned ub = __float_as_uint(b) + 0x8000u;
    return (ua >> 16) | (ub & 0xFFFF0000u);
}
__device__ __forceinline__ float fexp2(float x) {
#if __has_builtin(__builtin_amdgcn_exp2f)
    return __builtin_amdgcn_exp2f(x);
#else
    return exp2f(x);
#endif
}
// async global->LDS, 16B per lane (wave-uniform base + lane*16 dest)
__device__ __forceinline__ void gload_lds16(const void* g, void* l) {
    __builtin_amdgcn_global_load_lds(
        (const __attribute__((address_space(1))) unsigned int*)g,
        (__attribute__((address_space(3))) unsigned int*)l, 16, 0, 0);
}

// ---------------------------------------------------------------------------
// Kernel 1: W [K][N] fp32 -> WT [N][K] bf16 for Wq/Wk/Wv (blockIdx.z)
// ---------------------------------------------------------------------------
__global__ void wt_kernel(const float* __restrict__ Wq, const float* __restrict__ Wk,
                          const float* __restrict__ Wv, short* __restrict__ wt_base) {
    __shared__ float t[32][33];
    const float* W = (blockIdx.z == 0) ? Wq : (blockIdx.z == 1 ? Wk : Wv);
    short* WT = wt_base + (size_t)blockIdx.z * DM * DM;
    int kb = blockIdx.x * 32, nb = blockIdx.y * 32;
    int tx = threadIdx.x, ty = threadIdx.y;  // 32 x 8
#pragma unroll
    for (int r = 0; r < 4; r++)
        t[ty + 8 * r][tx] = W[(size_t)(kb + ty + 8 * r) * DM + nb + tx];
    __syncthreads();
#pragma unroll
    for (int r = 0; r < 4; r++)
        WT[(size_t)(nb + ty + 8 * r) * DM + kb + tx] = f2bf(t[tx][ty + 8 * r]);
}

// ---------------------------------------------------------------------------
// Kernel 2: fused projections (z = 0:Q, 1:K, 2:V).  [frozen from R5]
// 512-thr blocks, tile 128(M) x 256(N), BK=32; 8 waves, each the m97 body.
// LDS 48KB x2buf -> 3 blocks/CU; grid 768 = one dispatch round, no tail.
// Staging issued at iter top. Grid 1D chunked XCD swizzle (768 = 8 x 96).
// ---------------------------------------------------------------------------
__global__ __launch_bounds__(512, 2) void projf_kernel(
        const float* __restrict__ Xq, const float* __restrict__ Xk,
        const float* __restrict__ Xv, const short* __restrict__ WT3,
        const float* __restrict__ bq, const float* __restrict__ bk,
        const float* __restrict__ bv,
        short* __restrict__ Qh, short* __restrict__ Kh, short* __restrict__ Vt,
        float qscale) {
    __shared__ __align__(16) short As[2][128 * 32];   // bf16 A tile,  8KB/buf
    __shared__ __align__(16) short Bs[2][256 * 32];   // bf16 B tile, 16KB/buf
    const int bid = blockIdx.x;
    const int swz = (bid & 7) * 96 + (bid >> 3);
    const int nx = swz & 3;          // n-tile (fastest logical: 4 share X panel)
    const int my = (swz >> 2) & 63;  // m-tile
    const int z  = swz >> 8;         // matrix select (4*64 = 256 per z)

    const float* X = (z == 0) ? Xq : (z == 1) ? Xk : Xv;
    const short* WT = WT3 + (size_t)z * DM * DM;
    const float* bias = (z == 0) ? bq : (z == 1) ? bk : bv;
    short* out = (z == 0) ? Qh : (z == 1) ? Kh : Vt;
    const float scale = (z == 0) ? qscale : 1.0f;
    const int mode = (z == 2);

    const int tid = threadIdx.x;
    const int lane = tid & 63, w = tid >> 6;          // 8 waves
    const int l15 = lane & 15, quad = lane >> 4;
    const int n0 = nx * 256, m0 = my * 128;
    const int wm = (w & 1) * 64, wn = (w >> 1) * 64;  // 2M x 4N wave grid
    const int arow = tid >> 2;          // A staging: 4 threads/row
    const int ako  = (tid & 3) * 8;     // 8 floats (=8 bf16 out) per thread

    const float* xb = X + (size_t)m0 * DM;

    f32x4 acc[4][4];
#pragma unroll
    for (int i = 0; i < 4; i++)
#pragma unroll
        for (int j = 0; j < 4; j++) { acc[i][j][0] = 0.f; acc[i][j][1] = 0.f; acc[i][j][2] = 0.f; acc[i][j][3] = 0.f; }

    auto stageB = [&](int k0, int bi) {
#pragma unroll
        for (int it = 0; it < 2; it++) {
            int c = it * 512 + tid;
            int row = c >> 2, ko = (c & 3) * 8;
            gload_lds16(WT + (size_t)(n0 + row) * DM + k0 + ko, Bs[bi] + c * 8);
        }
    };

    // ---- prologue: stage tile 0 into buf 0 ----
    float4 a0, a1;
    a0 = *(const float4*)(xb + (size_t)arow * DM + ako);
    a1 = *(const float4*)(xb + (size_t)arow * DM + ako + 4);
    stageB(0, 0);
    {
        uint4 p;
        p.x = pk2bf(a0.x, a0.y); p.y = pk2bf(a0.z, a0.w);
        p.z = pk2bf(a1.x, a1.y); p.w = pk2bf(a1.z, a1.w);
        *(uint4*)(As[0] + arow * 32 + ako) = p;
    }

    for (int t = 0; t < 32; t++) {
        const int bi = t & 1;
        const int kn = t * 32 + 32;     // next tile's k0
        __syncthreads();                // tile t staged (vmcnt+lgkm drained)

        if (t < 31) {                   // STAGE AT TOP: max cover before use
            a0 = *(const float4*)(xb + (size_t)arow * DM + kn + ako);
            a1 = *(const float4*)(xb + (size_t)arow * DM + kn + ako + 4);
            stageB(kn, bi ^ 1);
        }

        short8 af[4], bf[4];
#pragma unroll
        for (int i = 0; i < 4; i++)
            af[i] = *(const short8*)(As[bi] + (wm + i * 16 + l15) * 32 + quad * 8);
#pragma unroll
        for (int j = 0; j < 4; j++)
            bf[j] = *(const short8*)(Bs[bi] + (wn + j * 16 + l15) * 32 + quad * 8);

#pragma unroll
        for (int i = 0; i < 4; i++)
#pragma unroll
            for (int j = 0; j < 4; j++)
                acc[i][j] = __builtin_amdgcn_mfma_f32_16x16x32_bf16(af[i], bf[j], acc[i][j], 0, 0, 0);

        if (t < 31) {                   // convert+write A for tile t+1
            uint4 p;
            p.x = pk2bf(a0.x, a0.y); p.y = pk2bf(a0.z, a0.w);
            p.z = pk2bf(a1.x, a1.y); p.w = pk2bf(a1.z, a1.w);
            *(uint4*)(As[bi ^ 1] + arow * 32 + ako) = p;
        }
    }

    // ---- epilogue ----
#pragma unroll
    for (int j = 0; j < 4; j++) {
        int col = n0 + wn + j * 16 + l15;
        float bv_ = bias[col];
        int h = col >> 6, d = col & 63;
#pragma unroll
        for (int i = 0; i < 4; i++) {
            int rowbase = m0 + wm + i * 16 + quad * 4;
            int bb = rowbase >> 11, s0 = rowbase & 2047;
            if (mode == 0) {
#pragma unroll
                for (int r = 0; r < 4; r++)
                    out[((size_t)(bb * NH + h) * S_LEN + (s0 + r)) * HD + d] =
                        f2bf((acc[i][j][r] + bv_) * scale);
            } else {
                short4v pk;
#pragma unroll
                for (int r = 0; r < 4; r++) pk[r] = f2bf((acc[i][j][r] + bv_) * scale);
                *(short4v*)(out + ((size_t)(bb * NH + h) * HD + d) * S_LEN + s0) = pk;
            }
        }
    }
}

// ---------------------------------------------------------------------------
// Kernel 3: attention, R6 restructure: SWAPPED QK^T + in-register P exchange.
// Rationale (R5 analysis): attn (~186us) is phase-locked-serialization-bound,
// not pipe-bound; the 36KB ps buffer forced 2 blocks/CU (one barrier domain
// pair) and a per-iter P->LDS->lgkmcnt(0)->read round-trip.
// Changes:
//  - QK^T computed as mfma(K,Q) (operand swap == output transpose): lane
//    holds P[q=l15][key=nb*16+quad*4+r] -- q-row is LANE-LOCAL.
//  - P->PV A-frag (lane needs P[q=l15][32hf+quad*8..+7]) via pk2bf r-pair
//    packing (r-adjacent == key-adjacent) + 8 __shfl + 4 selects per
//    (strip, k-half). No ps LDS, no lgkm drain.
//  - row-sum lsum is lane-local; reduced over quads (shfl_xor 16/32) once
//    after the loop; per-row inverse redistributed with one shfl.
//  - LDS 32KB (K/V only) -> 256-thr/4-wave blocks, q-tile 128, grid 1024 =
//    exactly 4 blocks/CU x 256 CU all resident; 4 independent barrier
//    domains/CU de-phase the exp2/MFMA/LDS bursts. launch_bounds(256,4).
// Grid 1D chunked XCD swizzle: 1024 = 8 XCDs x 128.
// ---------------------------------------------------------------------------
__global__ __launch_bounds__(256, 4) void attn_kernel(
        const short* __restrict__ Q, const short* __restrict__ K,
        const short* __restrict__ V, float* __restrict__ out) {
    __shared__ __align__(16) short Ks[2][2][64][32];  // [buf][d-half][key][32] 16KB
    __shared__ __align__(16) short Vs[2][2][64][32];  // [buf][k-half][d][32]   16KB
    const int bid = blockIdx.x;
    const int swz = (bid & 7) * 128 + (bid >> 3);
    const int qi = swz & 15;         // q-tile (fastest in logical order)
    const int h  = (swz >> 4) & 15;  // head
    const int b  = swz >> 8;         // batch

    const int tid = threadIdx.x;
    const int lane = tid & 63, w = tid >> 6;          // 4 waves
    const int l15 = lane & 15, quad = lane >> 4;
    const int q0 = qi * 128;
    const size_t bh = (size_t)(b * NH + h);
    const short* qp = Q + bh * S_LEN * HD;
    const short* kp = K + bh * S_LEN * HD;
    const short* vp = V + bh * (size_t)HD * S_LEN;

    short8 qa[2][2];
#pragma unroll
    for (int s = 0; s < 2; s++) {
        const short* qr = qp + (size_t)(q0 + w * 32 + s * 16 + l15) * HD + quad * 8;
        qa[s][0] = *(const short8*)(qr);
        qa[s][1] = *(const short8*)(qr + 32);
    }

    f32x4 o[2][4];
    float lsum[2] = {0.f, 0.f};
#pragma unroll
    for (int s = 0; s < 2; s++)
#pragma unroll
        for (int d = 0; d < 4; d++) {
            o[s][d][0] = 0.f; o[s][d][1] = 0.f; o[s][d][2] = 0.f; o[s][d][3] = 0.f;
        }

    // P-exchange source lanes (fixed per thread):
    //   dest u32 j of frag hf comes from quad_s = 2*(quad&1) (+1 for j>=2),
    //   variable nb = 2hf + (quad>>1) selected after the shuffle.
    const int srcLo = ((quad & 1) * 2) * 16 + l15;
    const int srcHi = srcLo + 16;

    auto stageKV = [&](int kt, int bi) {
        short* kd = &Ks[bi][0][0][0];
        short* vd = &Vs[bi][0][0][0];
#pragma unroll
        for (int it = 0; it < 2; it++) {
            int c = it * 256 + tid;                  // 512 slots x 16B = 8KB each
            int half = c >> 8, row = (c >> 2) & 63, chunk = c & 3;
            int co = half * 32 + chunk * 8;
            gload_lds16(kp + (size_t)(kt + row) * HD + co, kd + c * 8);
            gload_lds16(vp + (size_t)row * S_LEN + kt + co, vd + c * 8);
        }
    };

    stageKV(0, 0);

    for (int t = 0; t < 32; t++) {
        const int bi = t & 1;
        __syncthreads();                 // tile t ready (vmcnt drained); buf^1 free
        if (t < 31) stageKV((t + 1) << 6, bi ^ 1);   // issue next tile NOW

        // ---- K frags + SWAPPED QK^T: sacc = S^T block (keys x q) ----
        short8 kf[4][2];
#pragma unroll
        for (int nb = 0; nb < 4; nb++) {
            kf[nb][0] = *(const short8*)(&Ks[bi][0][nb * 16 + l15][quad * 8]);
            kf[nb][1] = *(const short8*)(&Ks[bi][1][nb * 16 + l15][quad * 8]);
        }
        f32x4 sacc[2][4];
#pragma unroll
        for (int nb = 0; nb < 4; nb++)
#pragma unroll
            for (int s = 0; s < 2; s++) {
                f32x4 zz; zz[0] = 0.f; zz[1] = 0.f; zz[2] = 0.f; zz[3] = 0.f;
                zz = __builtin_amdgcn_mfma_f32_16x16x32_bf16(kf[nb][0], qa[s][0], zz, 0, 0, 0);
                sacc[s][nb] = __builtin_amdgcn_mfma_f32_16x16x32_bf16(kf[nb][1], qa[s][1], zz, 0, 0, 0);
            }

        // ---- P = exp2(S'); lane-local row partial sums; pack r-pairs ----
        unsigned up[2][4][2];
#pragma unroll
        for (int s = 0; s < 2; s++)
#pragma unroll
            for (int nb = 0; nb < 4; nb++) {
                float p0 = fexp2(sacc[s][nb][0]);
                float p1 = fexp2(sacc[s][nb][1]);
                float p2 = fexp2(sacc[s][nb][2]);
                float p3 = fexp2(sacc[s][nb][3]);
                lsum[s] += (p0 + p1) + (p2 + p3);
                up[s][nb][0] = pk2bf(p0, p1);   // keys nb*16+quad*4 +0,+1
                up[s][nb][1] = pk2bf(p2, p3);   // keys nb*16+quad*4 +2,+3
            }

        // ---- in-register exchange: build PV A-frags ----
        short8 pa[2][2];
#pragma unroll
        for (int s = 0; s < 2; s++)
#pragma unroll
            for (int hf = 0; hf < 2; hf++) {
                unsigned a0 = (unsigned)__shfl((int)up[s][2 * hf][0], srcLo);
                unsigned a1 = (unsigned)__shfl((int)up[s][2 * hf][1], srcLo);
                unsigned a2 = (unsigned)__shfl((int)up[s][2 * hf][0], srcHi);
                unsigned a3 = (unsigned)__shfl((int)up[s][2 * hf][1], srcHi);
                unsigned b0 = (unsigned)__shfl((int)up[s][2 * hf + 1][0], srcLo);
                unsigned b1 = (unsigned)__shfl((int)up[s][2 * hf + 1][1], srcLo);
                unsigned b2 = (unsigned)__shfl((int)up[s][2 * hf + 1][0], srcHi);
                unsigned b3 = (unsigned)__shfl((int)up[s][2 * hf + 1][1], srcHi);
                const bool hi = (quad >> 1) != 0;   // nb select = 2hf + (quad>>1)
                uint4 uu;
                uu.x = hi ? b0 : a0;
                uu.y = hi ? b1 : a1;
                uu.z = hi ? b2 : a2;
                uu.w = hi ? b3 : a3;
                pa[s][hf] = *(short8*)&uu;
            }

        // ---- V frags from LDS + PV ----
#pragma unroll
        for (int dd = 0; dd < 4; dd++) {
            short8 v0 = *(const short8*)(&Vs[bi][0][dd * 16 + l15][quad * 8]);
            short8 v1 = *(const short8*)(&Vs[bi][1][dd * 16 + l15][quad * 8]);
#pragma unroll
            for (int s = 0; s < 2; s++) {
                o[s][dd] = __builtin_amdgcn_mfma_f32_16x16x32_bf16(pa[s][0], v0, o[s][dd], 0, 0, 0);
                o[s][dd] = __builtin_amdgcn_mfma_f32_16x16x32_bf16(pa[s][1], v1, o[s][dd], 0, 0, 0);
            }
        }
    }

    // ---- l reduction (across quads) + epilogue ----
    float inv[2];
#pragma unroll
    for (int s = 0; s < 2; s++) {
        float l = lsum[s];
        l += __shfl_xor(l, 16);
        l += __shfl_xor(l, 32);
        inv[s] = 1.f / l;
    }
#pragma unroll
    for (int s = 0; s < 2; s++) {
        float ir[4];
#pragma unroll
        for (int r = 0; r < 4; r++)
            ir[r] = __shfl(inv[s], quad * 4 + r);   // rowsum^-1 for q=quad*4+r
        float* orow = out + ((size_t)b * S_LEN + q0 + w * 32 + s * 16 + quad * 4) * DM + h * HD + l15;
#pragma unroll
        for (int r = 0; r < 4; r++)
#pragma unroll
            for (int dd = 0; dd < 4; dd++)
                orow[(size_t)r * DM + dd * 16] = o[s][dd][r] * ir[r];
    }
}

// ---------------------------------------------------------------------------
// ws (56.6 MB): [0,6.3M) WT x3 bf16 | Qh | Kh | Vt (16.8M each)
// ---------------------------------------------------------------------------
extern "C" void kernel_launch(void* const* d_in, const int* in_sizes, int n_in,
                              void* d_out, int out_size, void* d_ws, size_t ws_size,
                              hipStream_t stream) {
    const float* query  = (const float*)d_in[0];
    const float* key_in = (const float*)d_in[1];
    const float* value  = (const float*)d_in[2];
    const float* Wq = (const float*)d_in[3];
    const float* bq = (const float*)d_in[4];
    const float* Wk = (const float*)d_in[5];
    const float* bk = (const float*)d_in[6];
    const float* Wv = (const float*)d_in[7];
    const float* bv = (const float*)d_in[8];

    short* wt = (short*)d_ws;
    short* Qh = wt + 3 * 1048576;
    short* Kh = Qh + 8388608;
    short* Vt = Kh + 8388608;
    float* out = (float*)d_out;

    const float QSCALE = 0.125f * 1.44269504088896340736f;  // 1/sqrt(64) * log2(e)

    wt_kernel<<<dim3(32, 32, 3), dim3(32, 8), 0, stream>>>(Wq, Wk, Wv, wt);
    projf_kernel<<<dim3(768), 512, 0, stream>>>(query, key_in, value, wt,
                                                bq, bk, bv, Qh, Kh, Vt, QSCALE);
    attn_kernel<<<dim3(1024), 256, 0, stream>>>(Qh, Kh, Vt, out);
}